// Round 4
// baseline (68.024 us; speedup 1.0000x reference)
//
#include <hip/hip_runtime.h>
#include <cmath>

#define N_GAUSS 256

// ---------------------------------------------------------------------------
// Kernel 1: per-block partial min/max of coords (x,y). 64 blocks x 256 thr.
// Reads coords as float4 (two points per load). partial[block] =
// (minx, miny, maxx, maxy).
// ---------------------------------------------------------------------------
__global__ __launch_bounds__(256) void k_partial_minmax(
    const float4* __restrict__ coords4, int m /* n/2 float4 pairs */,
    const float2* __restrict__ coords, int n,
    float4* __restrict__ partial) {
  int tid = blockIdx.x * blockDim.x + threadIdx.x;
  int stride = gridDim.x * blockDim.x;
  float mnx = INFINITY, mny = INFINITY, mxx = -INFINITY, mxy = -INFINITY;
  for (int i = tid; i < m; i += stride) {
    float4 c = coords4[i];
    mnx = fminf(mnx, fminf(c.x, c.z));
    mny = fminf(mny, fminf(c.y, c.w));
    mxx = fmaxf(mxx, fmaxf(c.x, c.z));
    mxy = fmaxf(mxy, fmaxf(c.y, c.w));
  }
  // odd-n tail (n==131072 is even; generic safety)
  if (tid == 0 && (n & 1)) {
    float2 c = coords[n - 1];
    mnx = fminf(mnx, c.x);
    mny = fminf(mny, c.y);
    mxx = fmaxf(mxx, c.x);
    mxy = fmaxf(mxy, c.y);
  }
  for (int o = 32; o > 0; o >>= 1) {
    mnx = fminf(mnx, __shfl_down(mnx, o));
    mny = fminf(mny, __shfl_down(mny, o));
    mxx = fmaxf(mxx, __shfl_down(mxx, o));
    mxy = fmaxf(mxy, __shfl_down(mxy, o));
  }
  __shared__ float4 lds[4];
  if ((threadIdx.x & 63) == 0) lds[threadIdx.x >> 6] = make_float4(mnx, mny, mxx, mxy);
  __syncthreads();
  if (threadIdx.x == 0) {
    float4 r = lds[0];
    for (int w = 1; w < 4; ++w) {
      float4 o = lds[w];
      r.x = fminf(r.x, o.x);
      r.y = fminf(r.y, o.y);
      r.z = fmaxf(r.z, o.z);
      r.w = fmaxf(r.w, o.w);
    }
    partial[blockIdx.x] = r;
  }
}

__device__ __forceinline__ float sigmoidf_fast(float w) {
  float t = __builtin_amdgcn_exp2f(-1.4426950408889634f * w);
  return 1.0f / (1.0f + t);
}

// ---------------------------------------------------------------------------
// Kernel 2 (fused): per-block {reduce 64 partials -> bounds -> fp32 param
// fold into LDS}, then the early-exit main loop at TWO points per thread.
//
// Folded form: u = A*x + B*y + E, v = C*x + D*y + F, z = sqrt(u^2+v^2)
//   sp[2b] = (A,B,E,C), sp[2b+1] = (D,F,-,-)
//
// fp32 params safe: H is saturated at 1e-9 (sigma-term < 1e-24); O(1e-6)
// param perturbation moves H ~14 orders below the 2e-11 threshold.
// Early exit: kernel terms >= 0 so ks only grows; once every lane has both
// points' ks > 6, sigmoid(-10(ks-0.5)) < e^-55 and H == 1e-9 regardless of
// the skipped terms.
// ---------------------------------------------------------------------------
__global__ __launch_bounds__(256) void k_fused_main(
    const float4* __restrict__ coords4,
    const float2* __restrict__ coords,
    const float4* __restrict__ partial,
    const float* __restrict__ W_scale,
    const float* __restrict__ W_shape_var,
    const float* __restrict__ W_rotation,
    const float* __restrict__ W_offsets,
    float* __restrict__ out, int n) {
  __shared__ float4 sp[2 * N_GAUSS];
  __shared__ float4 lds4[4];
  __shared__ float4 boundsS;

  int t = threadIdx.x;

  // ---- reduce the 64 partials to global bounds (redundant per block) ----
  float4 r = (t < 64) ? partial[t]
                      : make_float4(INFINITY, INFINITY, -INFINITY, -INFINITY);
  for (int o = 32; o > 0; o >>= 1) {
    r.x = fminf(r.x, __shfl_down(r.x, o));
    r.y = fminf(r.y, __shfl_down(r.y, o));
    r.z = fmaxf(r.z, __shfl_down(r.z, o));
    r.w = fmaxf(r.w, __shfl_down(r.w, o));
  }
  if ((t & 63) == 0) lds4[t >> 6] = r;
  __syncthreads();
  if (t == 0) {
    float4 a = lds4[0];
    for (int w = 1; w < 4; ++w) {
      float4 o = lds4[w];
      a.x = fminf(a.x, o.x);
      a.y = fminf(a.y, o.y);
      a.z = fmaxf(a.z, o.z);
      a.w = fmaxf(a.w, o.w);
    }
    boundsS = a;
  }
  __syncthreads();
  float4 bc = boundsS;

  // ---- fp32 param fold: thread t handles gaussian t ----
  {
    float cmin0 = bc.x - bc.z * 0.05f;
    float cmin1 = bc.y - bc.w * 0.05f;
    float cmax0 = bc.z + bc.z * 0.05f;
    float cmax1 = bc.w + bc.w * 0.05f;

    float sS = sigmoidf_fast(W_scale[t]);
    float base_scale = 1.45f * sS + 0.05f;
    float sV = sigmoidf_fast(W_shape_var[t]);
    float ratio = 3.0f * sV + 0.5f;
    float sR = sigmoidf_fast(W_rotation[t]);
    const float PIf = 3.14159265358979323846f;
    float rot = -0.5f * PIf + PIf * sR;
    float sOx = sigmoidf_fast(W_offsets[2 * t]);
    float sOy = sigmoidf_fast(W_offsets[2 * t + 1]);
    float ox = cmin0 + (cmax0 - cmin0) * sOx;
    float oy = cmin1 + (cmax1 - cmin1) * sOy;

    float cr = cosf(rot), sr = sinf(rot);
    float inv_s = 1.0f / (base_scale + 1e-8f);
    float r0 = rsqrtf(1.0f + 1e-6f);              // sigma0 = 1
    float r1 = rsqrtf(fmaf(ratio, ratio, 1e-6f)); // sigma1 = ratio

    float A = r0 * cr * inv_s;
    float B = -r0 * sr * inv_s;
    float E = -fmaf(A, ox, B * oy);
    float C = r1 * sr * inv_s;
    float D = r1 * cr * inv_s;
    float F = -fmaf(C, ox, D * oy);

    sp[2 * t]     = make_float4(A, B, E, C);
    sp[2 * t + 1] = make_float4(D, F, 0.0f, 0.0f);
  }
  __syncthreads();

  // ---- main loop: two consecutive points per thread ----
  int gid = blockIdx.x * blockDim.x + threadIdx.x;
  int i0 = 2 * gid;
  if (i0 >= n) return;
  bool has2 = (i0 + 1) < n;

  float x0, y0, x1, y1;
  if (has2) {
    float4 c = coords4[gid];
    x0 = c.x; y0 = c.y; x1 = c.z; y1 = c.w;
  } else {
    float2 c = coords[i0];
    x0 = c.x; y0 = c.y; x1 = c.x; y1 = c.y; // duplicate; second result unused
  }

  float ks0 = 1e-8f, ks1 = 1e-8f;
  const float K1 = 14.4269504088896339f; // 10 * log2(e)

  for (int b0 = 0; b0 < N_GAUSS; b0 += 4) {
#pragma unroll
    for (int j = 0; j < 4; ++j) {
      int b = b0 + j;
      float4 p0 = sp[2 * b];
      float4 p1 = sp[2 * b + 1];
      float u0 = fmaf(p0.x, x0, fmaf(p0.y, y0, p0.z));
      float v0 = fmaf(p0.w, x0, fmaf(p1.x, y0, p1.y));
      float u1 = fmaf(p0.x, x1, fmaf(p0.y, y1, p0.z));
      float v1 = fmaf(p0.w, x1, fmaf(p1.x, y1, p1.y));
      float z0 = sqrtf(fmaf(u0, u0, v0 * v0));
      float z1 = sqrtf(fmaf(u1, u1, v1 * v1));
      float t0 = __builtin_amdgcn_exp2f(fmaf(K1, z0, -K1));
      float t1 = __builtin_amdgcn_exp2f(fmaf(K1, z1, -K1));
      ks0 += __builtin_amdgcn_rcpf(1.0f + t0);
      ks1 += __builtin_amdgcn_rcpf(1.0f + t1);
    }
    if (__all((ks0 > 6.0f) && (ks1 > 6.0f))) break;
  }

  // H = (1-1e-9) * sigmoid(-10*(ks-0.5)) + 1e-9
  float e0 = __builtin_amdgcn_exp2f(fmaf(K1, ks0, -0.5f * K1));
  float s0 = __builtin_amdgcn_rcpf(1.0f + e0);
  float h0 = fmaf(1e-9f, 1.0f - s0, s0);
  if (has2) {
    float e1 = __builtin_amdgcn_exp2f(fmaf(K1, ks1, -0.5f * K1));
    float s1 = __builtin_amdgcn_rcpf(1.0f + e1);
    float h1 = fmaf(1e-9f, 1.0f - s1, s1);
    ((float2*)out)[gid] = make_float2(h0, h1); // coalesced 8B store
  } else {
    out[i0] = h0;
  }
}

extern "C" void kernel_launch(void* const* d_in, const int* in_sizes, int n_in,
                              void* d_out, int out_size, void* d_ws, size_t ws_size,
                              hipStream_t stream) {
  const float* coords      = (const float*)d_in[0];
  const float* W_scale     = (const float*)d_in[1];
  const float* W_shape_var = (const float*)d_in[2];
  const float* W_rotation  = (const float*)d_in[3];
  const float* W_offsets   = (const float*)d_in[4];
  float* out = (float*)d_out;

  int n = in_sizes[0] / 2; // coords is (N,2)
  int m = n / 2;           // float4 pairs

  // workspace: [0,1024) partial min/max (64 float4)
  float4* partial = (float4*)d_ws;

  k_partial_minmax<<<64, 256, 0, stream>>>((const float4*)coords, m,
                                           (const float2*)coords, n, partial);
  int pairs = (n + 1) / 2;
  int blocks = (pairs + 255) / 256;
  k_fused_main<<<blocks, 256, 0, stream>>>((const float4*)coords,
                                           (const float2*)coords, partial,
                                           W_scale, W_shape_var, W_rotation,
                                           W_offsets, out, n);
}

// Round 5
// 67.641 us; speedup vs baseline: 1.0057x; 1.0057x over previous
//
#include <hip/hip_runtime.h>
#include <cmath>

#define N_GAUSS 256

// ---------------------------------------------------------------------------
// Kernel 1: per-block partial min/max of coords (x,y). 64 blocks x 256 thr,
// float4 loads (two points per load). partial[block] = (minx,miny,maxx,maxy).
// ---------------------------------------------------------------------------
__global__ __launch_bounds__(256) void k_partial_minmax(
    const float4* __restrict__ coords4, int m /* n/2 float4 pairs */,
    const float2* __restrict__ coords, int n,
    float4* __restrict__ partial) {
  int tid = blockIdx.x * blockDim.x + threadIdx.x;
  int stride = gridDim.x * blockDim.x;
  float mnx = INFINITY, mny = INFINITY, mxx = -INFINITY, mxy = -INFINITY;
  for (int i = tid; i < m; i += stride) {
    float4 c = coords4[i];
    mnx = fminf(mnx, fminf(c.x, c.z));
    mny = fminf(mny, fminf(c.y, c.w));
    mxx = fmaxf(mxx, fmaxf(c.x, c.z));
    mxy = fmaxf(mxy, fmaxf(c.y, c.w));
  }
  if (tid == 0 && (n & 1)) { // odd-n tail (n is even here; generic safety)
    float2 c = coords[n - 1];
    mnx = fminf(mnx, c.x);
    mny = fminf(mny, c.y);
    mxx = fmaxf(mxx, c.x);
    mxy = fmaxf(mxy, c.y);
  }
  for (int o = 32; o > 0; o >>= 1) {
    mnx = fminf(mnx, __shfl_down(mnx, o));
    mny = fminf(mny, __shfl_down(mny, o));
    mxx = fmaxf(mxx, __shfl_down(mxx, o));
    mxy = fmaxf(mxy, __shfl_down(mxy, o));
  }
  __shared__ float4 lds[4];
  if ((threadIdx.x & 63) == 0) lds[threadIdx.x >> 6] = make_float4(mnx, mny, mxx, mxy);
  __syncthreads();
  if (threadIdx.x == 0) {
    float4 r = lds[0];
    for (int w = 1; w < 4; ++w) {
      float4 o = lds[w];
      r.x = fminf(r.x, o.x);
      r.y = fminf(r.y, o.y);
      r.z = fmaxf(r.z, o.z);
      r.w = fmaxf(r.w, o.w);
    }
    partial[blockIdx.x] = r;
  }
}

__device__ __forceinline__ float sigmoidf_fast(float w) {
  float t = __builtin_amdgcn_exp2f(-1.4426950408889634f * w);
  return 1.0f / (1.0f + t);
}

// ---------------------------------------------------------------------------
// Kernel 2 (fused): per-block {reduce 64 partials -> bounds -> fp32 param
// fold into LDS}, then the early-exit main loop at ONE point per thread
// (measured best: R3 config; 2 pts/thread was neutral-negative in R4).
//
// Folded form: u = A*x + B*y + E, v = C*x + D*y + F, z = sqrt(u^2+v^2)
//   sp[2b] = (A,B,E,C), sp[2b+1] = (D,F,-,-)
//
// fp32 params safe: H is saturated at 1e-9 (sigma-term < 1e-24); O(1e-6)
// param perturbation moves H ~14 orders below the 2e-11 threshold.
// Early exit: kernel terms >= 0 so ks only grows; once every lane has
// ks > 6, sigmoid(-10(ks-0.5)) < e^-55 and H == 1e-9 regardless of the
// skipped terms.
// ---------------------------------------------------------------------------
__global__ __launch_bounds__(256) void k_fused_main(
    const float2* __restrict__ coords,
    const float4* __restrict__ partial,
    const float* __restrict__ W_scale,
    const float* __restrict__ W_shape_var,
    const float* __restrict__ W_rotation,
    const float* __restrict__ W_offsets,
    float* __restrict__ out, int n) {
  __shared__ float4 sp[2 * N_GAUSS];
  __shared__ float4 lds4[4];
  __shared__ float4 boundsS;

  int t = threadIdx.x;

  // ---- reduce the 64 partials to global bounds (redundant per block) ----
  float4 r = (t < 64) ? partial[t]
                      : make_float4(INFINITY, INFINITY, -INFINITY, -INFINITY);
  for (int o = 32; o > 0; o >>= 1) {
    r.x = fminf(r.x, __shfl_down(r.x, o));
    r.y = fminf(r.y, __shfl_down(r.y, o));
    r.z = fmaxf(r.z, __shfl_down(r.z, o));
    r.w = fmaxf(r.w, __shfl_down(r.w, o));
  }
  if ((t & 63) == 0) lds4[t >> 6] = r;
  __syncthreads();
  if (t == 0) {
    float4 a = lds4[0];
    for (int w = 1; w < 4; ++w) {
      float4 o = lds4[w];
      a.x = fminf(a.x, o.x);
      a.y = fminf(a.y, o.y);
      a.z = fmaxf(a.z, o.z);
      a.w = fmaxf(a.w, o.w);
    }
    boundsS = a;
  }
  __syncthreads();
  float4 bc = boundsS;

  // ---- fp32 param fold: thread t handles gaussian t ----
  {
    float cmin0 = bc.x - bc.z * 0.05f;
    float cmin1 = bc.y - bc.w * 0.05f;
    float cmax0 = bc.z + bc.z * 0.05f;
    float cmax1 = bc.w + bc.w * 0.05f;

    float sS = sigmoidf_fast(W_scale[t]);
    float base_scale = 1.45f * sS + 0.05f;
    float sV = sigmoidf_fast(W_shape_var[t]);
    float ratio = 3.0f * sV + 0.5f;
    float sR = sigmoidf_fast(W_rotation[t]);
    const float PIf = 3.14159265358979323846f;
    float rot = -0.5f * PIf + PIf * sR;
    float sOx = sigmoidf_fast(W_offsets[2 * t]);
    float sOy = sigmoidf_fast(W_offsets[2 * t + 1]);
    float ox = cmin0 + (cmax0 - cmin0) * sOx;
    float oy = cmin1 + (cmax1 - cmin1) * sOy;

    float cr = cosf(rot), sr = sinf(rot);
    float inv_s = 1.0f / (base_scale + 1e-8f);
    float r0 = rsqrtf(1.0f + 1e-6f);              // sigma0 = 1
    float r1 = rsqrtf(fmaf(ratio, ratio, 1e-6f)); // sigma1 = ratio

    float A = r0 * cr * inv_s;
    float B = -r0 * sr * inv_s;
    float E = -fmaf(A, ox, B * oy);
    float C = r1 * sr * inv_s;
    float D = r1 * cr * inv_s;
    float F = -fmaf(C, ox, D * oy);

    sp[2 * t]     = make_float4(A, B, E, C);
    sp[2 * t + 1] = make_float4(D, F, 0.0f, 0.0f);
  }
  __syncthreads();

  // ---- main loop: one point per thread, wave-uniform early exit ----
  int i = blockIdx.x * blockDim.x + threadIdx.x;
  if (i >= n) return;
  float2 c = coords[i];
  float x = c.x, y = c.y;
  float ks = 1e-8f;
  const float K1 = 14.4269504088896339f; // 10 * log2(e)

  for (int b0 = 0; b0 < N_GAUSS; b0 += 8) {
#pragma unroll
    for (int j = 0; j < 8; ++j) {
      int b = b0 + j;
      float4 p0 = sp[2 * b];
      float4 p1 = sp[2 * b + 1];
      float u = fmaf(p0.x, x, fmaf(p0.y, y, p0.z));
      float v = fmaf(p0.w, x, fmaf(p1.x, y, p1.y));
      float z = sqrtf(fmaf(u, u, v * v));
      float tt = __builtin_amdgcn_exp2f(fmaf(K1, z, -K1));
      ks += __builtin_amdgcn_rcpf(1.0f + tt);
    }
    if (__all(ks > 6.0f)) break;
  }

  // H = (1-1e-9) * sigmoid(-10*(ks-0.5)) + 1e-9
  float t2 = __builtin_amdgcn_exp2f(fmaf(K1, ks, -0.5f * K1));
  float s = __builtin_amdgcn_rcpf(1.0f + t2);
  out[i] = fmaf(1e-9f, 1.0f - s, s);
}

extern "C" void kernel_launch(void* const* d_in, const int* in_sizes, int n_in,
                              void* d_out, int out_size, void* d_ws, size_t ws_size,
                              hipStream_t stream) {
  const float* coords      = (const float*)d_in[0];
  const float* W_scale     = (const float*)d_in[1];
  const float* W_shape_var = (const float*)d_in[2];
  const float* W_rotation  = (const float*)d_in[3];
  const float* W_offsets   = (const float*)d_in[4];
  float* out = (float*)d_out;

  int n = in_sizes[0] / 2; // coords is (N,2)
  int m = n / 2;           // float4 pairs

  // workspace: [0,1024) partial min/max (64 float4)
  float4* partial = (float4*)d_ws;

  k_partial_minmax<<<64, 256, 0, stream>>>((const float4*)coords, m,
                                           (const float2*)coords, n, partial);
  int blocks = (n + 255) / 256;
  k_fused_main<<<blocks, 256, 0, stream>>>((const float2*)coords, partial,
                                           W_scale, W_shape_var, W_rotation,
                                           W_offsets, out, n);
}